// Round 1
// baseline (591.685 us; speedup 1.0000x reference)
//
#include <hip/hip_runtime.h>
#include <math.h>

// SwitchGate: T=16384, D=4096, E=64, CAP_RATE=2.4.
// capacity = ceil(2.4*16384) = 39322 > T  =>  pruning never triggers:
//   pruned_idx == top1_idx, n_valid == T.
// loss = (E / T^2) * sum_e count[e] * score_sum[e]
//
// d_out (float32): [0,T) pruned_idx (as float) | [T,2T) top1_score | [2T] loss
//
// Round-5 design: occupancy. Round-4 counters: Occupancy=23% (grid 256 = 1
// block/CU, 8 waves), VALUBusy=25.6%, HBM 8% -> latency-bound. Fix: split
// the 64 experts across waves so acc[] drops 64->32 and unified regs fit the
// <=64-VGPR budget for 32 waves/CU.
//  - Main: 512 blocks x 1024 thr (16 waves). block = (token-group tg, expert
//    half eh); wave w = k-split (KSPLIT=16, 256 k each), lanes = 64 tokens,
//    acc[32] experts. W rows via wave-uniform pointer -> s_load_dwordx16
//    (2 per k = 32 SGPRs; leaves SGPR room for the compiler to pipeline).
//    __launch_bounds__(1024, 8) forces the 64-VGPR budget -> 2 blocks/CU.
//  - Split-K combined in LDS (L[64][33], banks (lane+e)%32: conflict-free),
//    half-tile written exclusively (no atomics) to global Lg[T][64] (4 MB).
//  - eh = bid>>8 so the two halves of a tg land on the SAME XCD (bid%8) and
//    share A through L2; all 512 blocks co-resident.
//  - New epilogue kernel (256 x 512) does bias+softmax+top1+loss partials
//    from Lg (L2/L3-resident, ~4 MB): same math as the old in-block epilogue.

#define T_TOK 16384
#define D_DIM 4096
#define E_EXP 64
#define KSPLIT 16
#define KPW (D_DIM / KSPLIT)   // 256 k per wave

typedef float v16f __attribute__((ext_vector_type(16)));

// ---------------------------------------------------------------- zero ws
__global__ void zero_ws_kernel(float* __restrict__ wsf, int* __restrict__ wsc) {
    int t = threadIdx.x;
    if (t < 64) wsf[t] = 0.0f;
    else if (t < 128) wsc[t - 64] = 0;
}

// ---------------------------------------------------------------- W -> WT
__global__ __launch_bounds__(256) void transpose_w_kernel(
    const float* __restrict__ W, float* __restrict__ WT) {
    const int gid = blockIdx.x * 256 + threadIdx.x;  // 0..262143
    const int k = gid >> 6;
    const int e = gid & 63;
    WT[gid] = W[(size_t)e * D_DIM + k];
}

// ---------------------------------------------------------------- main
__global__ __launch_bounds__(1024, 8) void gate_main_kernel(
    const float* __restrict__ inp,   // [T, D]
    const float* __restrict__ WT,    // [D, E] transposed weights
    float* __restrict__ Lg)          // [T, E] logits (no bias)
{
    __shared__ float L[64][33];      // logits [token_local][expert_local]

    const int tid  = threadIdx.x;
    const int lane = tid & 63;       // token
    const int wid  = tid >> 6;       // 0..15, k-split id
    const int tg   = blockIdx.x & 255;   // token group
    const int eh   = blockIdx.x >> 8;    // expert half; pairs (b, b+256)
                                         // share XCD (b%8) -> A shared in L2
    const int tok  = tg * 64 + lane;
    // wave-uniform by construction -> enables SMEM selection for W loads
    const int kb0  = __builtin_amdgcn_readfirstlane(wid * KPW);
    const int e0   = eh * 32;

    float* Lf = &L[0][0];
    for (int i = tid; i < 64 * 33; i += 1024) Lf[i] = 0.0f;
    __syncthreads();

    float acc[32];
#pragma unroll
    for (int e = 0; e < 32; ++e) acc[e] = 0.0f;

    const float* a_ptr = inp + (size_t)tok * D_DIM + kb0;        // per-lane
    const float* wt0   = WT + (size_t)kb0 * E_EXP + e0;          // uniform

    for (int kb = 0; kb < KPW; kb += 8) {
        const float4 A0 = *(const float4*)(a_ptr + kb);
        const float4 A1 = *(const float4*)(a_ptr + kb + 4);
        const float av[8] = {A0.x, A0.y, A0.z, A0.w, A1.x, A1.y, A1.z, A1.w};
#pragma unroll
        for (int kk = 0; kk < 8; ++kk) {
            const v16f* wp = (const v16f*)(wt0 + (size_t)(kb + kk) * E_EXP);
            const v16f w0 = wp[0];
            const v16f w1 = wp[1];
            const float a = av[kk];
#pragma unroll
            for (int j = 0; j < 16; ++j) {
                acc[j]      += a * w0[j];
                acc[j + 16] += a * w1[j];
            }
        }
    }

    // combine split-K partials; banks (lane*33+e)%32 = (lane+e)%32: clean
#pragma unroll
    for (int e = 0; e < 32; ++e)
        atomicAdd(&L[lane][e], acc[e]);
    __syncthreads();

    // write exclusive 64x32 half-tile to global logits (coalesced 128B rows)
    const int r = tid >> 5;          // 0..31
    const int c = tid & 31;
    const size_t base = ((size_t)tg * 64) * E_EXP + e0 + c;
    Lg[base + (size_t)r * E_EXP]        = L[r][c];
    Lg[base + (size_t)(r + 32) * E_EXP] = L[r + 32][c];
}

// ---------------------------------------------------------------- epilogue
__global__ __launch_bounds__(512) void gate_epilogue_kernel(
    const float* __restrict__ Lg,    // [T, E]
    const float* __restrict__ b,     // [E]
    float* __restrict__ out,         // [2T+1]
    float* __restrict__ g_sum,       // [64]
    int*   __restrict__ g_cnt)       // [64]
{
    __shared__ float bs[64];
    __shared__ int   bc[64];
    const int tid  = threadIdx.x;
    const int lane = tid & 63;       // expert
    const int wid  = tid >> 6;       // 0..7, token sub-group
    if (tid < 64) { bs[tid] = 0.0f; bc[tid] = 0; }
    __syncthreads();

    const float bias = b[lane];
    float priv_sum = 0.0f;
    int   priv_cnt = 0;
#pragma unroll
    for (int t = 0; t < 8; ++t) {
        const int gt = blockIdx.x * 64 + 8 * wid + t;
        const float l = Lg[(size_t)gt * E_EXP + lane] + bias;

        float mv = l; int mi = lane;   // ties -> lowest index (lax.top_k)
#pragma unroll
        for (int off = 1; off < 64; off <<= 1) {
            const float ov = __shfl_xor(mv, off, 64);
            const int   oi = __shfl_xor(mi, off, 64);
            if (ov > mv || (ov == mv && oi < mi)) { mv = ov; mi = oi; }
        }

        const float ex = __expf(l - mv);
        float s = ex;
#pragma unroll
        for (int off = 1; off < 64; off <<= 1) s += __shfl_xor(s, off, 64);
        const float inv = 1.0f / s;    // top-1 score

        if (lane == 0) {
            out[gt]         = (float)mi;   // never capacity-pruned
            out[T_TOK + gt] = inv;
        }
        priv_sum += ex * inv;              // softmax prob of expert `lane`
        priv_cnt += (mi == lane) ? 1 : 0;
    }

    atomicAdd(&bs[lane], priv_sum);
    atomicAdd(&bc[lane], priv_cnt);
    __syncthreads();
    if (tid < 64) {
        atomicAdd(&g_sum[tid], bs[tid]);
        atomicAdd(&g_cnt[tid], bc[tid]);
    }
}

// ---------------------------------------------------------------- loss
__global__ void gate_loss_kernel(const float* __restrict__ g_sum,
                                 const int* __restrict__ g_cnt,
                                 float* __restrict__ out) {
    const int e = threadIdx.x;   // 64 threads = 1 wave
    float v = g_sum[e] * (float)g_cnt[e];
#pragma unroll
    for (int off = 32; off > 0; off >>= 1) v += __shfl_xor(v, off, 64);
    if (e == 0)
        out[2 * T_TOK] = v * (float)E_EXP / ((float)T_TOK * (float)T_TOK);
}

// ---------------------------------------------------------------- launch
extern "C" void kernel_launch(void* const* d_in, const int* in_sizes, int n_in,
                              void* d_out, int out_size, void* d_ws, size_t ws_size,
                              hipStream_t stream) {
    const float* inp = (const float*)d_in[0];
    const float* W   = (const float*)d_in[1];
    const float* b   = (const float*)d_in[2];
    float* out = (float*)d_out;

    // ws layout: [0,1MB) WT | [1MB) g_sum(64f) g_cnt(64i) | [1MB+64KB) Lg 4MB
    float* WT    = (float*)d_ws;
    float* g_sum = (float*)((char*)d_ws + (1 << 20));
    int*   g_cnt = (int*)(g_sum + 64);
    float* Lg    = (float*)((char*)d_ws + (1 << 20) + (1 << 16));

    zero_ws_kernel<<<1, 128, 0, stream>>>(g_sum, g_cnt);
    transpose_w_kernel<<<(D_DIM * E_EXP) / 256, 256, 0, stream>>>(W, WT);
    gate_main_kernel<<<512, 1024, 0, stream>>>(inp, WT, Lg);
    gate_epilogue_kernel<<<T_TOK / 64, 512, 0, stream>>>(Lg, b, out, g_sum, g_cnt);
    gate_loss_kernel<<<1, 64, 0, stream>>>(g_sum, g_cnt, out);
}

// Round 4
// 501.440 us; speedup vs baseline: 1.1800x; 1.1800x over previous
//
#include <hip/hip_runtime.h>
#include <math.h>

// SwitchGate: T=16384, D=4096, E=64, CAP_RATE=2.4.
// capacity = ceil(2.4*16384) = 39322 > T  =>  pruning never triggers:
//   pruned_idx == top1_idx, n_valid == T.
// loss = (E / T^2) * sum_e count[e] * score_sum[e]
//
// d_out (float32): [0,T) pruned_idx (as float) | [T,2T) top1_score | [2T] loss
//
// Round-8 = Round-6/7 resubmitted (both benches were infra failures: the
// container died before producing any kernel signal; round-5 proved 1024-thr
// blocks run fine on this harness, so the kernel is not the trigger).
// Design: round-4's A-read-once decomposition (64 tokens per block, full 64
// experts per lane, W rows via wave-uniform s_load), with latency fixes:
//  - Round-4: 512 thr = 2 waves/SIMD, VALUBusy 25.6% -> per-wave stalls
//    (lgkmcnt on 4x s_load_dwordx16 per k-row, vmcnt on A float4s) exposed.
//  - Round-5: expert-split doubled+ A fetch (815 MB vs 256 MB) -> regressed.
//  - Now: KSPLIT=16 -> 1024 thr, 16 waves/block, grid 256 = 1 block/CU =
//    4 waves/SIMD (50% occ). acc[64] + prefetch regs ~= 95-120 VGPR, under
//    the 128 cap a 1024-thr block implies. A loads explicitly software-
//    pipelined one kb ahead so HBM latency hides under the 1024 issue-cycles
//    of the previous FMA block. A is read exactly once (256 MB).
//  - Split-K partials combined via LDS ds_add_f32 on a 65-padded tile
//    (banks (lane+e)%32 -> conflict-free), softmax/top1/loss in-block.

#define T_TOK 16384
#define D_DIM 4096
#define E_EXP 64
#define KSPLIT 16
#define KPW (D_DIM / KSPLIT)   // 256 k per wave

typedef float v16f __attribute__((ext_vector_type(16)));

// ---------------------------------------------------------------- zero ws
__global__ void zero_ws_kernel(float* __restrict__ wsf, int* __restrict__ wsc) {
    int t = threadIdx.x;
    if (t < 64) wsf[t] = 0.0f;
    else if (t < 128) wsc[t - 64] = 0;
}

// ---------------------------------------------------------------- W -> WT
__global__ __launch_bounds__(256) void transpose_w_kernel(
    const float* __restrict__ W, float* __restrict__ WT) {
    const int gid = blockIdx.x * 256 + threadIdx.x;  // 0..262143
    const int k = gid >> 6;
    const int e = gid & 63;
    WT[gid] = W[(size_t)e * D_DIM + k];
}

// ---------------------------------------------------------------- main
__global__ __launch_bounds__(1024, 4) void gate_main_kernel(
    const float* __restrict__ inp,   // [T, D]
    const float* __restrict__ WT,    // [D, E] transposed weights
    const float* __restrict__ b,     // [E]
    float* __restrict__ out,         // [2T+1]
    float* __restrict__ g_sum,       // [64]
    int*   __restrict__ g_cnt)       // [64]
{
    __shared__ float L[64][65];      // logits [token_local][expert], padded
    __shared__ float bs[64];
    __shared__ int   bc[64];

    const int tid  = threadIdx.x;
    const int lane = tid & 63;       // token (main loop), expert (epilogue)
    const int wid  = tid >> 6;       // 0..15, k-split id
    const int tok  = blockIdx.x * 64 + lane;
    // wave-uniform by construction -> enables SMEM selection for W loads
    const int kb0  = __builtin_amdgcn_readfirstlane(wid * KPW);

    float* Lf = &L[0][0];
    for (int i = tid; i < 64 * 65; i += 1024) Lf[i] = 0.0f;
    if (tid < 64) { bs[tid] = 0.0f; bc[tid] = 0; }
    __syncthreads();

    float acc[E_EXP];
#pragma unroll
    for (int e = 0; e < E_EXP; ++e) acc[e] = 0.0f;

    const float* a_ptr   = inp + (size_t)tok * D_DIM + kb0;         // per-lane
    const v16f*  wt_base = (const v16f*)(WT + (size_t)kb0 * E_EXP); // uniform

    // software-pipelined A stream: load kb+8 while FMAing kb
    float4 A0 = *(const float4*)(a_ptr);
    float4 A1 = *(const float4*)(a_ptr + 4);
    for (int kb = 0; kb < KPW; kb += 8) {
        const int nxt = (kb + 8 < KPW) ? (kb + 8) : 0;   // last iter: dummy
        const float4 N0 = *(const float4*)(a_ptr + nxt);
        const float4 N1 = *(const float4*)(a_ptr + nxt + 4);
        const float av[8] = {A0.x, A0.y, A0.z, A0.w, A1.x, A1.y, A1.z, A1.w};
#pragma unroll
        for (int kk = 0; kk < 8; ++kk) {
            const v16f* wp = wt_base + (size_t)(kb + kk) * 4;  // 64 floats/row
            const v16f w0 = wp[0];
            const v16f w1 = wp[1];
            const v16f w2 = wp[2];
            const v16f w3 = wp[3];
            const float a = av[kk];
#pragma unroll
            for (int j = 0; j < 16; ++j) {
                acc[j]      += a * w0[j];
                acc[j + 16] += a * w1[j];
                acc[j + 32] += a * w2[j];
                acc[j + 48] += a * w3[j];
            }
        }
        A0 = N0; A1 = N1;
    }

    // combine split-K partials; banks (lane*65+e)%32 = (lane+e)%32: clean
#pragma unroll
    for (int e = 0; e < E_EXP; ++e)
        atomicAdd(&L[lane][e], acc[e]);
    __syncthreads();

    // ---- epilogue: wave wid handles tokens 4*wid..4*wid+3; lane = expert ----
    const float bias = b[lane];
    float priv_sum = 0.0f;
    int   priv_cnt = 0;
#pragma unroll
    for (int t = 0; t < 4; ++t) {
        const int tl = 4 * wid + t;
        const float l = L[tl][lane] + bias;

        float mv = l; int mi = lane;   // ties -> lowest index (lax.top_k)
#pragma unroll
        for (int off = 1; off < 64; off <<= 1) {
            const float ov = __shfl_xor(mv, off, 64);
            const int   oi = __shfl_xor(mi, off, 64);
            if (ov > mv || (ov == mv && oi < mi)) { mv = ov; mi = oi; }
        }

        const float ex = __expf(l - mv);
        float s = ex;
#pragma unroll
        for (int off = 1; off < 64; off <<= 1) s += __shfl_xor(s, off, 64);
        const float inv = 1.0f / s;    // top-1 score

        if (lane == 0) {
            const int gt = blockIdx.x * 64 + tl;
            out[gt]         = (float)mi;   // never capacity-pruned
            out[T_TOK + gt] = inv;
        }
        priv_sum += ex * inv;              // softmax prob of expert `lane`
        priv_cnt += (mi == lane) ? 1 : 0;
    }

    atomicAdd(&bs[lane], priv_sum);
    atomicAdd(&bc[lane], priv_cnt);
    __syncthreads();
    if (tid < 64) {
        atomicAdd(&g_sum[tid], bs[tid]);
        atomicAdd(&g_cnt[tid], bc[tid]);
    }
}

// ---------------------------------------------------------------- loss
__global__ void gate_loss_kernel(const float* __restrict__ g_sum,
                                 const int* __restrict__ g_cnt,
                                 float* __restrict__ out) {
    const int e = threadIdx.x;   // 64 threads = 1 wave
    float v = g_sum[e] * (float)g_cnt[e];
#pragma unroll
    for (int off = 32; off > 0; off >>= 1) v += __shfl_xor(v, off, 64);
    if (e == 0)
        out[2 * T_TOK] = v * (float)E_EXP / ((float)T_TOK * (float)T_TOK);
}

// ---------------------------------------------------------------- launch
extern "C" void kernel_launch(void* const* d_in, const int* in_sizes, int n_in,
                              void* d_out, int out_size, void* d_ws, size_t ws_size,
                              hipStream_t stream) {
    const float* inp = (const float*)d_in[0];
    const float* W   = (const float*)d_in[1];
    const float* b   = (const float*)d_in[2];
    float* out = (float*)d_out;

    float* WT    = (float*)d_ws;                         // 1 MB transposed W
    float* g_sum = (float*)((char*)d_ws + (1 << 20));    // 64 floats
    int*   g_cnt = (int*)(g_sum + 64);                   // 64 ints

    zero_ws_kernel<<<1, 128, 0, stream>>>(g_sum, g_cnt);
    transpose_w_kernel<<<(D_DIM * E_EXP) / 256, 256, 0, stream>>>(W, WT);
    gate_main_kernel<<<T_TOK / 64, 1024, 0, stream>>>(inp, WT, b, out, g_sum, g_cnt);
    gate_loss_kernel<<<1, 64, 0, stream>>>(g_sum, g_cnt, out);
}

// Round 5
// 466.091 us; speedup vs baseline: 1.2695x; 1.0758x over previous
//
#include <hip/hip_runtime.h>
#include <math.h>

// SwitchGate: T=16384, D=4096, E=64, CAP_RATE=2.4.
// capacity = ceil(2.4*16384) = 39322 > T  =>  pruning never triggers:
//   pruned_idx == top1_idx, n_valid == T.
// loss = (E / T^2) * sum_e count[e] * score_sum[e]
//
// d_out (float32): [0,T) pruned_idx (as float) | [T,2T) top1_score | [2T] loss
//
// Round-9 design: register-tiled fp32 GEMM, both operands via vector/LDS.
// Evidence: R4 vs R0 showed VALUBusy pinned at ~26% at BOTH 8 and 16
// waves/CU -> the scalar-memory pipe (W via s_load per k-row, lgkmcnt(0)
// drain) is a shared saturated resource; W must leave the scalar pipe.
//  - 256 blocks x 256 thr (4 waves). Block = 64 tok x 64 exp, full K.
//    Waves split K (1024 each); each wave stages its own 16-k chunk of
//    A^T (4KB) + WT (4KB) into private LDS -> NO barriers in main loop.
//  - Lane owns an 8x8 (token x expert) tile: per k, 4x ds_read_b128
//    (8-way broadcast, conflict-free) + 64 v_fmac. ds:VALU = 4:128cy.
//  - T14 pipeline: issue next chunk's 8 global float4 loads BEFORE the
//    FMA block, ds_write after (HBM latency hides under 2048cy of FMA).
//  - Partials combined via LDS atomicAdd into L[64][65]; softmax/top1/
//    loss epilogue in-block (4 waves x 16 tokens).
// Floors: VALU 54.6us, HBM 41us (A=256MB once; W L2-resident per XCD).

#define T_TOK 16384
#define D_DIM 4096
#define E_EXP 64
#define NW 4                    // waves per block (k-split)
#define KPW (D_DIM / NW)        // 1024 k per wave
#define BK 16                   // k per staged chunk
#define NCH (KPW / BK)          // 64 chunks per wave

// ---------------------------------------------------- W -> WT (+ zero ws)
__global__ __launch_bounds__(256) void transpose_w_kernel(
    const float* __restrict__ W, float* __restrict__ WT,
    float* __restrict__ g_sum, int* __restrict__ g_cnt) {
    __shared__ float Tt[64][65];
    const int tid = threadIdx.x;
    if (blockIdx.x == 0) {
        if (tid < 64) g_sum[tid] = 0.0f;
        else if (tid < 128) g_cnt[tid - 64] = 0;
    }
    const int k0 = blockIdx.x * 64;
#pragma unroll
    for (int i = 0; i < 16; ++i) {          // coalesced read along k
        const int idx = tid + 256 * i;      // 0..4095
        const int e = idx >> 6, kl = idx & 63;
        Tt[kl][e] = W[(size_t)e * D_DIM + k0 + kl];
    }
    __syncthreads();
#pragma unroll
    for (int i = 0; i < 16; ++i) {          // coalesced write along e
        const int idx = tid + 256 * i;
        const int kl = idx >> 6, e = idx & 63;
        WT[(size_t)(k0 + kl) * E_EXP + e] = Tt[kl][e];
    }
}

// ---------------------------------------------------------------- main
__global__ __launch_bounds__(256) void gate_main_kernel(
    const float* __restrict__ inp,   // [T, D]
    const float* __restrict__ WT,    // [D, E] transposed weights
    const float* __restrict__ b,     // [E]
    float* __restrict__ out,         // [2T+1]
    float* __restrict__ g_sum,       // [64]
    int*   __restrict__ g_cnt)       // [64]
{
    __shared__ float AT[NW][BK][64]; // per-wave A^T chunk [k][token]
    __shared__ float WS[NW][BK][64]; // per-wave W chunk  [k][expert]
    __shared__ float L[64][65];      // logits [token][expert], padded
    __shared__ float bs[64];
    __shared__ int   bc[64];

    const int tid  = threadIdx.x;
    const int lane = tid & 63;
    const int wid  = tid >> 6;       // 0..3, k-split id
    const int r    = lane >> 3;      // token-group 0..7 (tokens 8r..8r+7)
    const int c    = lane & 7;       // expert-group 0..7 (experts 8c..8c+7)
    const int tok0 = blockIdx.x * 64;

    float* Lf = &L[0][0];
    for (int i = tid; i < 64 * 65; i += 256) Lf[i] = 0.0f;
    if (tid < 64) { bs[tid] = 0.0f; bc[tid] = 0; }
    __syncthreads();

    float acc[64];
#pragma unroll
    for (int i = 0; i < 64; ++i) acc[i] = 0.0f;

    // per-lane A row (lane = token), per-wave k-range
    const float* arow = inp + (size_t)(tok0 + lane) * D_DIM + (size_t)wid * KPW;
    const float* wrow = WT + (size_t)wid * KPW * E_EXP;

    // ---- prologue: stage chunk 0 ----
    {
        const float4* ap = (const float4*)arow;
        const float4 a0 = ap[0], a1 = ap[1], a2 = ap[2], a3 = ap[3];
        const float4* wp = (const float4*)wrow;
        const float4 w0 = wp[lane], w1 = wp[64 + lane],
                     w2 = wp[128 + lane], w3 = wp[192 + lane];
        AT[wid][ 0][lane] = a0.x; AT[wid][ 1][lane] = a0.y;
        AT[wid][ 2][lane] = a0.z; AT[wid][ 3][lane] = a0.w;
        AT[wid][ 4][lane] = a1.x; AT[wid][ 5][lane] = a1.y;
        AT[wid][ 6][lane] = a1.z; AT[wid][ 7][lane] = a1.w;
        AT[wid][ 8][lane] = a2.x; AT[wid][ 9][lane] = a2.y;
        AT[wid][10][lane] = a2.z; AT[wid][11][lane] = a2.w;
        AT[wid][12][lane] = a3.x; AT[wid][13][lane] = a3.y;
        AT[wid][14][lane] = a3.z; AT[wid][15][lane] = a3.w;
        float4* wsp = (float4*)&WS[wid][0][0];
        wsp[lane] = w0; wsp[64 + lane] = w1;
        wsp[128 + lane] = w2; wsp[192 + lane] = w3;
    }

    // ---- main loop: load ch+1 early, FMA ch, write ch+1 late ----
    for (int ch = 0; ch < NCH; ++ch) {
        float4 na0, na1, na2, na3, nw0, nw1, nw2, nw3;
        const bool more = (ch + 1 < NCH);
        if (more) {
            const float4* ap = (const float4*)(arow + (ch + 1) * BK);
            na0 = ap[0]; na1 = ap[1]; na2 = ap[2]; na3 = ap[3];
            const float4* wp = (const float4*)(wrow + (size_t)(ch + 1) * BK * E_EXP);
            nw0 = wp[lane]; nw1 = wp[64 + lane];
            nw2 = wp[128 + lane]; nw3 = wp[192 + lane];
        }
#pragma unroll
        for (int k = 0; k < BK; ++k) {
            const float4 af0 = *(const float4*)&AT[wid][k][8 * r];
            const float4 af1 = *(const float4*)&AT[wid][k][8 * r + 4];
            const float4 wf0 = *(const float4*)&WS[wid][k][8 * c];
            const float4 wf1 = *(const float4*)&WS[wid][k][8 * c + 4];
            const float av[8] = {af0.x, af0.y, af0.z, af0.w,
                                 af1.x, af1.y, af1.z, af1.w};
            const float wv[8] = {wf0.x, wf0.y, wf0.z, wf0.w,
                                 wf1.x, wf1.y, wf1.z, wf1.w};
#pragma unroll
            for (int i = 0; i < 8; ++i)
#pragma unroll
                for (int j = 0; j < 8; ++j)
                    acc[i * 8 + j] += av[i] * wv[j];
        }
        if (more) {
            AT[wid][ 0][lane] = na0.x; AT[wid][ 1][lane] = na0.y;
            AT[wid][ 2][lane] = na0.z; AT[wid][ 3][lane] = na0.w;
            AT[wid][ 4][lane] = na1.x; AT[wid][ 5][lane] = na1.y;
            AT[wid][ 6][lane] = na1.z; AT[wid][ 7][lane] = na1.w;
            AT[wid][ 8][lane] = na2.x; AT[wid][ 9][lane] = na2.y;
            AT[wid][10][lane] = na2.z; AT[wid][11][lane] = na2.w;
            AT[wid][12][lane] = na3.x; AT[wid][13][lane] = na3.y;
            AT[wid][14][lane] = na3.z; AT[wid][15][lane] = na3.w;
            float4* wsp = (float4*)&WS[wid][0][0];
            wsp[lane] = nw0; wsp[64 + lane] = nw1;
            wsp[128 + lane] = nw2; wsp[192 + lane] = nw3;
        }
    }

    // ---- combine k-split partials into L ----
#pragma unroll
    for (int i = 0; i < 8; ++i)
#pragma unroll
        for (int j = 0; j < 8; ++j)
            atomicAdd(&L[8 * r + i][8 * c + j], acc[i * 8 + j]);
    __syncthreads();

    // ---- epilogue: wave wid handles tokens 16*wid..16*wid+15; lane=expert --
    const float bias = b[lane];
    float priv_sum = 0.0f;
    int   priv_cnt = 0;
#pragma unroll
    for (int t = 0; t < 16; ++t) {
        const int tl = 16 * wid + t;
        const float l = L[tl][lane] + bias;

        float mv = l; int mi = lane;   // ties -> lowest index (lax.top_k)
#pragma unroll
        for (int off = 1; off < 64; off <<= 1) {
            const float ov = __shfl_xor(mv, off, 64);
            const int   oi = __shfl_xor(mi, off, 64);
            if (ov > mv || (ov == mv && oi < mi)) { mv = ov; mi = oi; }
        }

        const float ex = __expf(l - mv);
        float s = ex;
#pragma unroll
        for (int off = 1; off < 64; off <<= 1) s += __shfl_xor(s, off, 64);
        const float inv = 1.0f / s;    // top-1 score

        if (lane == 0) {
            const int gt = tok0 + tl;
            out[gt]         = (float)mi;   // never capacity-pruned
            out[T_TOK + gt] = inv;
        }
        priv_sum += ex * inv;              // softmax prob of expert `lane`
        priv_cnt += (mi == lane) ? 1 : 0;
    }

    atomicAdd(&bs[lane], priv_sum);
    atomicAdd(&bc[lane], priv_cnt);
    __syncthreads();
    if (tid < 64) {
        atomicAdd(&g_sum[tid], bs[tid]);
        atomicAdd(&g_cnt[tid], bc[tid]);
    }
}

// ---------------------------------------------------------------- loss
__global__ void gate_loss_kernel(const float* __restrict__ g_sum,
                                 const int* __restrict__ g_cnt,
                                 float* __restrict__ out) {
    const int e = threadIdx.x;   // 64 threads = 1 wave
    float v = g_sum[e] * (float)g_cnt[e];
#pragma unroll
    for (int off = 32; off > 0; off >>= 1) v += __shfl_xor(v, off, 64);
    if (e == 0)
        out[2 * T_TOK] = v * (float)E_EXP / ((float)T_TOK * (float)T_TOK);
}

// ---------------------------------------------------------------- launch
extern "C" void kernel_launch(void* const* d_in, const int* in_sizes, int n_in,
                              void* d_out, int out_size, void* d_ws, size_t ws_size,
                              hipStream_t stream) {
    const float* inp = (const float*)d_in[0];
    const float* W   = (const float*)d_in[1];
    const float* b   = (const float*)d_in[2];
    float* out = (float*)d_out;

    float* WT    = (float*)d_ws;                         // 1 MB transposed W
    float* g_sum = (float*)((char*)d_ws + (1 << 20));    // 64 floats
    int*   g_cnt = (int*)(g_sum + 64);                   // 64 ints

    transpose_w_kernel<<<D_DIM / 64, 256, 0, stream>>>(W, WT, g_sum, g_cnt);
    gate_main_kernel<<<T_TOK / 64, 256, 0, stream>>>(inp, WT, b, out, g_sum, g_cnt);
    gate_loss_kernel<<<1, 64, 0, stream>>>(g_sum, g_cnt, out);
}